// Round 4
// baseline (243.457 us; speedup 1.0000x reference)
//
#include <hip/hip_runtime.h>
#include <math.h>

// (B,L,H,P) = (4,4096,512,512)
#define Bz 4
#define Lz 4096
#define Hz 512
#define Pz 512
#define Nz (Bz*Lz)          // 16384 rows
#define CL 64               // scan chunk length
#define NC (Lz/CL)          // 64 chunks
#define CS (Bz*NC*Pz)       // 131072 carry slots
#define EPSf 1e-5f

typedef unsigned short u16;
typedef unsigned int   u32;
typedef __attribute__((ext_vector_type(8))) short bf16x8;
typedef __attribute__((ext_vector_type(4))) float f32x4;

__device__ __forceinline__ float gelu_exact(float x){
    return 0.5f * x * (1.0f + erff(x * 0.70710678118654752f));
}
__device__ __forceinline__ u16 f2b(float f){
    union { float f; u32 u; } v; v.f = f;
    u32 u = v.u;
    u32 r = (u + 0x7FFFu + ((u >> 16) & 1u)) >> 16;   // RTNE
    return (u16)r;
}
__device__ __forceinline__ float b2f(u16 h){
    union { u32 u; float f; } v; v.u = ((u32)h) << 16; return v.f;
}

__device__ __forceinline__ void gload_lds16(const u16* g, u16* l){
    __builtin_amdgcn_global_load_lds(
        (const __attribute__((address_space(1))) void*)g,
        (__attribute__((address_space(3))) void*)l, 16, 0, 0);
}

// ---------------- setup: per-state SSM params ----------------
__global__ void setup_kernel(const float* __restrict__ Lre, const float* __restrict__ Lim,
                             const float* __restrict__ log_step,
                             float* __restrict__ prm){
    int p = blockIdx.x*blockDim.x + threadIdx.x;
    if (p >= Pz) return;
    float lr = Lre[p], li = Lim[p];
    float dt = expf(log_step[p]);
    float ar = lr*dt, ai = li*dt;
    float e = expf(ar);
    float Abr = e*cosf(ai), Abi = e*sinf(ai);   // Lambda_bar
    prm[p]        = Abr;
    prm[Pz + p]   = Abi;
    float nr = Abr - 1.0f, ni = Abi;
    float d2 = lr*lr + li*li;
    prm[2*Pz + p] = (nr*lr + ni*li)/d2;   // fRe
    prm[3*Pz + p] = (ni*lr - nr*li)/d2;   // fIm
    float arC = ar*(float)CL, aiC = ai*(float)CL;
    float eC = expf(arC);
    prm[4*Pz + p] = eC*cosf(aiC);         // ApowRe
    prm[5*Pz + p] = eC*sinf(aiC);         // ApowIm
}

// ---------------- merged weight converts (one launch) ----------------
__global__ __launch_bounds__(256) void cvt_all(const float* __restrict__ B_re,
                                               const float* __restrict__ B_im,
                                               const float* __restrict__ C_re,
                                               const float* __restrict__ C_im,
                                               const float* __restrict__ W_enc,
                                               const float* __restrict__ W_dec,
                                               u16* __restrict__ Bcat,
                                               u16* __restrict__ Ccat,
                                               u16* __restrict__ Wenc,
                                               u16* __restrict__ Wdec){
    const int Q = 512*512;
    int i = blockIdx.x*256 + threadIdx.x;
    if (i < Q){ Bcat[i] = f2b(B_re[i]); return; }
    i -= Q;
    if (i < Q){ Bcat[Q + i] = f2b(B_im[i]); return; }
    i -= Q;
    if (i < Q){
        int h = i >> 9, p = i & 511;
        Ccat[(size_t)h*1024 + p]       = f2b(C_re[i]);
        Ccat[(size_t)h*1024 + 512 + p] = f2b(-C_im[i]);
        return;
    }
    i -= Q;
    if (i < 2*Q){ Wenc[i] = f2b(W_enc[i]); return; }
    i -= 2*Q;
    Wdec[i] = f2b(W_dec[i]);
}

// ---------------- LayerNorm: f32 in -> bf16 out (+ optional f32 out) ----------------
__global__ __launch_bounds__(256) void ln_kernel(const float* __restrict__ in,
                                                 const float* __restrict__ w,
                                                 const float* __restrict__ b,
                                                 u16* __restrict__ ob,
                                                 float* __restrict__ of){
    int row = blockIdx.x;
    int tid = threadIdx.x;
    const float* r = in + (size_t)row*Hz;
    float v0 = r[tid], v1 = r[tid+256];
    float s = v0+v1, q = v0*v0+v1*v1;
    #pragma unroll
    for (int o=32;o;o>>=1){ s += __shfl_down(s,o); q += __shfl_down(q,o); }
    __shared__ float ss[4], sq[4];
    __shared__ float mu_s, rs_s;
    int wid = tid>>6, lane = tid&63;
    if (lane==0){ ss[wid]=s; sq[wid]=q; }
    __syncthreads();
    if (tid==0){
        float S=ss[0]+ss[1]+ss[2]+ss[3];
        float Q=sq[0]+sq[1]+sq[2]+sq[3];
        float mu = S/(float)Hz;
        float var = Q/(float)Hz - mu*mu;
        mu_s = mu; rs_s = rsqrtf(var + EPSf);
    }
    __syncthreads();
    float mu = mu_s, rs = rs_s;
    float r0 = (v0-mu)*rs*w[tid]    +b[tid];
    float r1 = (v1-mu)*rs*w[tid+256]+b[tid+256];
    u16* o = ob + (size_t)row*Hz;
    o[tid] = f2b(r0); o[tid+256] = f2b(r1);
    if (of){
        float* p = of + (size_t)row*Hz;
        p[tid] = r0; p[tid+256] = r1;
    }
}

// ============ 8-phase counted-vmcnt MFMA GEMM =============
// C[N,M] = A[N,K] @ Bw[M,K]^T. Tile 256x256, BK=64, 512 threads (8 waves, 1M x 8N).
// Per wave: C rows 0..255 (16 m-frags), cols w*32 (2 n-frags). acc[16][2] f32x4.
// K-tile phases: p0(mh0,k0) p1(mh0,k1) p2(mh1,k0) p3(mh1,k1), 16 MFMA each.
// Stages: (T,p0)->B(T+1) 4 loads; (T,p1)->A0(T+1) 2; (T,p2)->A1(T+1) 2.
// Waits: end-p1 vmcnt(6); end-p3 vmcnt(2). Never 0 in steady state.
// LDS tiles [256][64] bf16 with T2 swizzle byte ^= ((row&7)<<4); linear
// global_load_lds dest + inverse-swizzled global source (involution).
#define EB16 0
#define EY   1
#define ERES 2

#define SBAR() __builtin_amdgcn_s_barrier()

// stage 64 rows x 64 cols bf16 (8KB) with pre-swizzled source; 1 gload/thread
__device__ __forceinline__ void stage64(const u16* __restrict__ src, int ld,
                                        int grow0, int kt, u16* ldsQ){
    int lane = threadIdx.x & 63;
    int w    = threadIdx.x >> 6;
    int r    = w*8 + (lane >> 3);                      // 0..63
    int colE = 8*((lane & 7) ^ ((lane >> 3) & 7));     // swizzled source col (elems)
    const u16* g = src + (size_t)(grow0 + r)*ld + kt + colE;
    gload_lds16(g, ldsQ + w*512);                      // +lane*16B by HW
}

template<int K, int EPI>
__global__ __launch_bounds__(512)
void gemm8p(const u16* __restrict__ A, const u16* __restrict__ Bw, int M,
            u16* __restrict__ outB,
            float* hf,                          // EY: read fx / write h (aliased)
            const float* __restrict__ Dv,       // EY
            const u16* __restrict__ resB,       // ERES
            float* __restrict__ outF)           // ERES
{
    constexpr int NT = K/64;
    __shared__ u16 AL[2][256*64];
    __shared__ u16 BL[2][256*64];

    // XCD-aware bijective swizzle (nwg % 8 == 0 for all our grids)
    int nx = gridDim.x, ny = gridDim.y;
    int nwg = nx*ny;
    int lid = blockIdx.x + blockIdx.y*nx;
    int cpx = nwg >> 3;
    int gdx = (lid & 7)*cpx + (lid >> 3);
    int n0 = (gdx / ny) * 256;
    int m0 = (gdx % ny) * 256;

    int l = threadIdx.x & 63;
    int w = threadIdx.x >> 6;
    int lrow  = l & 15;
    int lcol0 = ((l >> 4)*8) ^ ((l & 7) << 3);   // u16 idx within 64-col row, ks=0
    int lcol1 = lcol0 ^ 32;                      // ks=1

    f32x4 acc[16][2];
    #pragma unroll
    for (int i=0;i<16;++i){ acc[i][0]=(f32x4)(0.f); acc[i][1]=(f32x4)(0.f); }

    // prologue: B(0) x4, A0(0) x2, A1(0) x2 ; wait all but A1(0)
    #pragma unroll
    for (int q=0;q<4;++q) stage64(Bw, K, m0+q*64, 0, &BL[0][q*4096]);
    stage64(A, K, n0+0,   0, &AL[0][0]);
    stage64(A, K, n0+64,  0, &AL[0][4096]);
    stage64(A, K, n0+128, 0, &AL[0][8192]);
    stage64(A, K, n0+192, 0, &AL[0][12288]);
    asm volatile("s_waitcnt vmcnt(2)" ::: "memory");
    SBAR();

    bf16x8 b0[2], b1[2];
    for (int T = 0; T < NT; ++T){
        int buf = T & 1, nb = buf ^ 1;
        int ktn = (T+1)*64;
        bool pf = (T+1 < NT);
        const u16* Ab = &AL[buf][0];
        const u16* Bb = &BL[buf][0];

        // ---- p0: mh=0, ks=0 ----
        {
            bf16x8 af[8];
            #pragma unroll
            for (int f=0; f<8; ++f) af[f] = *(const bf16x8*)&Ab[(f*16 + lrow)*64 + lcol0];
            #pragma unroll
            for (int fn=0; fn<2; ++fn) b0[fn] = *(const bf16x8*)&Bb[(w*32 + fn*16 + lrow)*64 + lcol0];
            if (pf){
                #pragma unroll
                for (int q=0;q<4;++q) stage64(Bw, K, m0+q*64, ktn, &BL[nb][q*4096]);
            }
            SBAR();
            __builtin_amdgcn_s_setprio(1);
            #pragma unroll
            for (int f=0; f<8; ++f)
                #pragma unroll
                for (int fn=0; fn<2; ++fn)
                    acc[f][fn] = __builtin_amdgcn_mfma_f32_16x16x32_bf16(af[f], b0[fn], acc[f][fn], 0,0,0);
            __builtin_amdgcn_s_setprio(0);
            SBAR();
        }
        // ---- p1: mh=0, ks=1 ----
        {
            bf16x8 af[8];
            #pragma unroll
            for (int f=0; f<8; ++f) af[f] = *(const bf16x8*)&Ab[(f*16 + lrow)*64 + lcol1];
            #pragma unroll
            for (int fn=0; fn<2; ++fn) b1[fn] = *(const bf16x8*)&Bb[(w*32 + fn*16 + lrow)*64 + lcol1];
            if (pf){
                stage64(A, K, n0+0,  ktn, &AL[nb][0]);
                stage64(A, K, n0+64, ktn, &AL[nb][4096]);
            }
            SBAR();
            __builtin_amdgcn_s_setprio(1);
            #pragma unroll
            for (int f=0; f<8; ++f)
                #pragma unroll
                for (int fn=0; fn<2; ++fn)
                    acc[f][fn] = __builtin_amdgcn_mfma_f32_16x16x32_bf16(af[f], b1[fn], acc[f][fn], 0,0,0);
            __builtin_amdgcn_s_setprio(0);
            if (pf) { asm volatile("s_waitcnt vmcnt(6)" ::: "memory"); }
            else    { asm volatile("s_waitcnt vmcnt(0)" ::: "memory"); }
            SBAR();
        }
        // ---- p2: mh=1, ks=0 ----
        {
            bf16x8 af[8];
            #pragma unroll
            for (int f=0; f<8; ++f) af[f] = *(const bf16x8*)&Ab[(128 + f*16 + lrow)*64 + lcol0];
            if (pf){
                stage64(A, K, n0+128, ktn, &AL[nb][8192]);
                stage64(A, K, n0+192, ktn, &AL[nb][12288]);
            }
            SBAR();
            __builtin_amdgcn_s_setprio(1);
            #pragma unroll
            for (int f=0; f<8; ++f)
                #pragma unroll
                for (int fn=0; fn<2; ++fn)
                    acc[8+f][fn] = __builtin_amdgcn_mfma_f32_16x16x32_bf16(af[f], b0[fn], acc[8+f][fn], 0,0,0);
            __builtin_amdgcn_s_setprio(0);
            SBAR();
        }
        // ---- p3: mh=1, ks=1 ----
        {
            bf16x8 af[8];
            #pragma unroll
            for (int f=0; f<8; ++f) af[f] = *(const bf16x8*)&Ab[(128 + f*16 + lrow)*64 + lcol1];
            SBAR();
            __builtin_amdgcn_s_setprio(1);
            #pragma unroll
            for (int f=0; f<8; ++f)
                #pragma unroll
                for (int fn=0; fn<2; ++fn)
                    acc[8+f][fn] = __builtin_amdgcn_mfma_f32_16x16x32_bf16(af[f], b1[fn], acc[8+f][fn], 0,0,0);
            __builtin_amdgcn_s_setprio(0);
            if (pf) { asm volatile("s_waitcnt vmcnt(2)" ::: "memory"); }
            SBAR();
        }
    }

    // epilogue: C layout col=lane&15, row=(lane>>4)*4+q
    int er = (l >> 4) * 4;
    int ec = l & 15;
    #pragma unroll
    for (int fm=0; fm<16; ++fm)
        #pragma unroll
        for (int fn=0; fn<2; ++fn)
            #pragma unroll
            for (int q=0; q<4; ++q){
                int n = n0 + fm*16 + er + q;
                int m = m0 + w*32 + fn*16 + ec;
                float v = acc[fm][fn][q];
                if (EPI == EB16){
                    outB[(size_t)n*M + m] = f2b(v);
                } else if (EPI == EY){
                    size_t idx = (size_t)n*Hz + m;
                    float fxv = hf[idx];
                    float y = 2.0f*v + Dv[m]*fxv;
                    hf[idx] = gelu_exact(y) + fxv;
                } else {
                    size_t idx = (size_t)n*Hz + m;
                    outF[idx] = v + b2f(resB[idx]);
                }
            }
}

// ---------------- scan (f folded in, bf16 I/O, f32 state) ----------------
// g layout: [N][1024], cols [0,512)=Re raw, [512,1024)=Im raw
__global__ __launch_bounds__(256) void scan_phase1(const u16* __restrict__ g,
                                                   const float* __restrict__ prm,
                                                   float* __restrict__ ERe,
                                                   float* __restrict__ EIm){
    int t = blockIdx.x;
    int pb = t & 1; t >>= 1;
    int c  = t % NC; t /= NC;
    int b  = t;
    int p  = pb*256 + threadIdx.x;
    size_t base = ((size_t)(b*Lz + c*CL))*1024 + p;
    float Ar = prm[p], Ai = prm[Pz+p];
    float fre = prm[2*Pz+p], fim = prm[3*Pz+p];
    float xr = 0.f, xi = 0.f;
    for (int ll = 0; ll < CL; ++ll) {
        float gr = b2f(g[base]), gi = b2f(g[base+512]);
        float br = fre*gr - fim*gi;
        float bi = fre*gi + fim*gr;
        float nr = Ar*xr - Ai*xi + br;
        float ni = Ar*xi + Ai*xr + bi;
        xr = nr; xi = ni;
        base += 1024;
    }
    size_t ci = ((size_t)(b*NC + c))*Pz + p;
    ERe[ci] = xr; EIm[ci] = xi;
}

__global__ __launch_bounds__(256) void scan_combine(const float* __restrict__ ERe,
                                                    const float* __restrict__ EIm,
                                                    const float* __restrict__ prm,
                                                    float* __restrict__ SinRe,
                                                    float* __restrict__ SinIm){
    int gt = blockIdx.x*256 + threadIdx.x;   // over B*P
    int b = gt / Pz, p = gt % Pz;
    float Ar = prm[4*Pz+p], Ai = prm[5*Pz+p];
    float Sr = 0.f, Si = 0.f;
    for (int c = 0; c < NC; ++c) {
        size_t idx = ((size_t)(b*NC + c))*Pz + p;
        SinRe[idx] = Sr; SinIm[idx] = Si;
        float er = ERe[idx], ei = EIm[idx];
        float nr = Ar*Sr - Ai*Si + er;
        float ni = Ar*Si + Ai*Sr + ei;
        Sr = nr; Si = ni;
    }
}

// overwrites g with xs (bf16, same [re|im] layout)
__global__ __launch_bounds__(256) void scan_phase2(u16* __restrict__ g,
                                                   const float* __restrict__ prm,
                                                   const float* __restrict__ SinRe,
                                                   const float* __restrict__ SinIm){
    int t = blockIdx.x;
    int pb = t & 1; t >>= 1;
    int c  = t % NC; t /= NC;
    int b  = t;
    int p  = pb*256 + threadIdx.x;
    size_t base = ((size_t)(b*Lz + c*CL))*1024 + p;
    size_t ci = ((size_t)(b*NC + c))*Pz + p;
    float Ar = prm[p], Ai = prm[Pz+p];
    float fre = prm[2*Pz+p], fim = prm[3*Pz+p];
    float xr = SinRe[ci], xi = SinIm[ci];
    for (int ll = 0; ll < CL; ++ll) {
        float gr = b2f(g[base]), gi = b2f(g[base+512]);
        float br = fre*gr - fim*gi;
        float bi = fre*gi + fim*gr;
        float nr = Ar*xr - Ai*xi + br;
        float ni = Ar*xi + Ai*xr + bi;
        xr = nr; xi = ni;
        g[base] = f2b(xr); g[base+512] = f2b(xi);
        base += 1024;
    }
}

// ---------------- GEGLU elementwise: ff = a * gelu(g) ----------------
__global__ __launch_bounds__(256) void geglu_kernel(const u16* __restrict__ e,
                                                    u16* __restrict__ ff){
    size_t i = (size_t)blockIdx.x*256 + threadIdx.x;  // over N*512
    int n = (int)(i >> 9), m = (int)(i & 511);
    float a = b2f(e[(size_t)n*1024 + m]);
    float gg = b2f(e[(size_t)n*1024 + 512 + m]);
    ff[i] = f2b(a * gelu_exact(gg));
}

extern "C" void kernel_launch(void* const* d_in, const int* in_sizes, int n_in,
                              void* d_out, int out_size, void* d_ws, size_t ws_size,
                              hipStream_t stream) {
    const float* x        = (const float*)d_in[0];
    const float* ln1_w    = (const float*)d_in[1];
    const float* ln1_b    = (const float*)d_in[2];
    const float* Lre      = (const float*)d_in[3];
    const float* Lim      = (const float*)d_in[4];
    const float* B_re     = (const float*)d_in[5];
    const float* B_im     = (const float*)d_in[6];
    const float* C_re     = (const float*)d_in[7];
    const float* C_im     = (const float*)d_in[8];
    const float* Dv       = (const float*)d_in[9];
    const float* log_step = (const float*)d_in[10];
    const float* ln2_w    = (const float*)d_in[11];
    const float* ln2_b    = (const float*)d_in[12];
    const float* W_enc    = (const float*)d_in[13];
    const float* W_dec    = (const float*)d_in[14];
    float* out = (float*)d_out;

    const size_t NH = (size_t)Nz*Hz;   // 8388608
    char* W = (char*)d_ws;
    float* fxf  = (float*)(W);                    // [N,512] f32 : fx, then h (in place)
    u16*   fxb  = (u16*)  (W + NH*4);             // [N,512] bf16: fx, then ff
    u16*   g    = (u16*)  (W + NH*6);             // [N,1024] bf16: g -> xs -> e
    u16*   fx2b = (u16*)  (W + NH*10);            // [N,512] bf16: fx2
    float* ERe  = (float*)(W + NH*12);
    float* EIm  = ERe + CS;
    float* SinRe= EIm + CS;
    float* SinIm= SinRe + CS;
    float* prm  = SinIm + CS;                     // 6*Pz f32
    u16*   Bcat = (u16*)(prm + 6*Pz);             // [1024,512]
    u16*   Ccat = Bcat + 1024*512;                // [512,1024]
    u16*   Wenc = Ccat + 512*1024;                // [1024,512]
    u16*   Wdec = Wenc + 1024*512;                // [512,512]

    setup_kernel<<<dim3(2), dim3(256), 0, stream>>>(Lre, Lim, log_step, prm);

    cvt_all<<<dim3(6*1024), dim3(256), 0, stream>>>(B_re, B_im, C_re, C_im, W_enc, W_dec,
                                                    Bcat, Ccat, Wenc, Wdec);

    // LN1: x -> fxb (bf16) + fxf (f32)
    ln_kernel<<<dim3(Nz), dim3(256), 0, stream>>>(x, ln1_w, ln1_b, fxb, fxf);

    // GEMM1: g = fxb @ Bcat^T   [N,1024]
    gemm8p<512,EB16><<<dim3(Nz/256, 1024/256), dim3(512), 0, stream>>>(
        fxb, Bcat, 1024, g, nullptr, nullptr, nullptr, nullptr);

    // scan: g (raw) -> xs (in place), f-scaling applied on load
    scan_phase1<<<dim3(Bz*NC*2), dim3(256), 0, stream>>>(g, prm, ERe, EIm);
    scan_combine<<<dim3((Bz*Pz)/256), dim3(256), 0, stream>>>(ERe, EIm, prm, SinRe, SinIm);
    scan_phase2<<<dim3(Bz*NC*2), dim3(256), 0, stream>>>(g, prm, SinRe, SinIm);

    // GEMM2 (Y): h = gelu(2*(xs@Ccat^T) + D*fx) + fx, in-place over fxf
    gemm8p<1024,EY><<<dim3(Nz/256, 512/256), dim3(512), 0, stream>>>(
        g, Ccat, 512, nullptr, fxf, Dv, nullptr, nullptr);

    // LN2: h -> fx2b (bf16 only)
    ln_kernel<<<dim3(Nz), dim3(256), 0, stream>>>(fxf, ln2_w, ln2_b, fx2b, nullptr);

    // GEMM3: e = fx2b @ Wenc^T  [N,1024]  (over g slot)
    gemm8p<512,EB16><<<dim3(Nz/256, 1024/256), dim3(512), 0, stream>>>(
        fx2b, Wenc, 1024, g, nullptr, nullptr, nullptr, nullptr);

    // GEGLU: ff = a * gelu(gg)  (over fxb slot)
    geglu_kernel<<<dim3((unsigned)(NH/256)), dim3(256), 0, stream>>>(g, fxb);

    // GEMM4: out = ff @ Wdec^T + fx2
    gemm8p<512,ERES><<<dim3(Nz/256, 512/256), dim3(512), 0, stream>>>(
        fxb, Wdec, 512, nullptr, nullptr, nullptr, fx2b, out);
}

// Round 5
// 195.827 us; speedup vs baseline: 1.2432x; 1.2432x over previous
//
#include <hip/hip_runtime.h>
#include <math.h>

// (B,L,H,P) = (4,4096,512,512)
#define Bz 4
#define Lz 4096
#define Hz 512
#define Pz 512
#define Nz (Bz*Lz)          // 16384 rows
#define CL 64               // scan chunk length
#define NC (Lz/CL)          // 64 chunks
#define CS (Bz*NC*Pz)       // 131072 carry slots
#define EPSf 1e-5f

typedef unsigned short u16;
typedef unsigned int   u32;
typedef __attribute__((ext_vector_type(8))) short bf16x8;
typedef __attribute__((ext_vector_type(4))) float f32x4;

__device__ __forceinline__ float gelu_exact(float x){
    return 0.5f * x * (1.0f + erff(x * 0.70710678118654752f));
}
__device__ __forceinline__ u16 f2b(float f){
    union { float f; u32 u; } v; v.f = f;
    u32 u = v.u;
    u32 r = (u + 0x7FFFu + ((u >> 16) & 1u)) >> 16;   // RTNE
    return (u16)r;
}
__device__ __forceinline__ float b2f(u16 h){
    union { u32 u; float f; } v; v.u = ((u32)h) << 16; return v.f;
}
__device__ __forceinline__ float cvt_in(float x){ return x; }
__device__ __forceinline__ float cvt_in(u16 x){ return b2f(x); }

__device__ __forceinline__ void gload_lds16(const u16* g, u16* l){
    __builtin_amdgcn_global_load_lds(
        (const __attribute__((address_space(1))) void*)g,
        (__attribute__((address_space(3))) void*)l, 16, 0, 0);
}

// ---------------- setup: per-state SSM params ----------------
__global__ void setup_kernel(const float* __restrict__ Lre, const float* __restrict__ Lim,
                             const float* __restrict__ log_step,
                             float* __restrict__ prm){
    int p = blockIdx.x*blockDim.x + threadIdx.x;
    if (p >= Pz) return;
    float lr = Lre[p], li = Lim[p];
    float dt = expf(log_step[p]);
    float ar = lr*dt, ai = li*dt;
    float e = expf(ar);
    float Abr = e*cosf(ai), Abi = e*sinf(ai);   // Lambda_bar
    prm[p]        = Abr;
    prm[Pz + p]   = Abi;
    float nr = Abr - 1.0f, ni = Abi;
    float d2 = lr*lr + li*li;
    prm[2*Pz + p] = (nr*lr + ni*li)/d2;   // fRe
    prm[3*Pz + p] = (ni*lr - nr*li)/d2;   // fIm
    float arC = ar*(float)CL, aiC = ai*(float)CL;
    float eC = expf(arC);
    prm[4*Pz + p] = eC*cosf(aiC);         // ApowRe
    prm[5*Pz + p] = eC*sinf(aiC);         // ApowIm
}

// ---------------- merged weight converts (one launch) ----------------
__global__ __launch_bounds__(256) void cvt_all(const float* __restrict__ B_re,
                                               const float* __restrict__ B_im,
                                               const float* __restrict__ C_re,
                                               const float* __restrict__ C_im,
                                               const float* __restrict__ W_enc,
                                               const float* __restrict__ W_dec,
                                               u16* __restrict__ Bcat,
                                               u16* __restrict__ Ccat,
                                               u16* __restrict__ Wenc,
                                               u16* __restrict__ Wdec){
    const int Q = 512*512;
    int i = blockIdx.x*256 + threadIdx.x;
    if (i < Q){ Bcat[i] = f2b(B_re[i]); return; }
    i -= Q;
    if (i < Q){ Bcat[Q + i] = f2b(B_im[i]); return; }
    i -= Q;
    if (i < Q){
        int h = i >> 9, p = i & 511;
        Ccat[(size_t)h*1024 + p]       = f2b(C_re[i]);
        Ccat[(size_t)h*1024 + 512 + p] = f2b(-C_im[i]);
        return;
    }
    i -= Q;
    if (i < 2*Q){ Wenc[i] = f2b(W_enc[i]); return; }
    i -= 2*Q;
    Wdec[i] = f2b(W_dec[i]);
}

// ---------------- LayerNorm: (f32|bf16) in -> bf16 out ----------------
template<typename T>
__global__ __launch_bounds__(256) void ln_kernel(const T* __restrict__ in,
                                                 const float* __restrict__ w,
                                                 const float* __restrict__ b,
                                                 u16* __restrict__ ob){
    int row = blockIdx.x;
    int tid = threadIdx.x;
    const T* r = in + (size_t)row*Hz;
    float v0 = cvt_in(r[tid]), v1 = cvt_in(r[tid+256]);
    float s = v0+v1, q = v0*v0+v1*v1;
    #pragma unroll
    for (int o=32;o;o>>=1){ s += __shfl_down(s,o); q += __shfl_down(q,o); }
    __shared__ float ss[4], sq[4];
    __shared__ float mu_s, rs_s;
    int wid = tid>>6, lane = tid&63;
    if (lane==0){ ss[wid]=s; sq[wid]=q; }
    __syncthreads();
    if (tid==0){
        float S=ss[0]+ss[1]+ss[2]+ss[3];
        float Q=sq[0]+sq[1]+sq[2]+sq[3];
        float mu = S/(float)Hz;
        float var = Q/(float)Hz - mu*mu;
        mu_s = mu; rs_s = rsqrtf(var + EPSf);
    }
    __syncthreads();
    float mu = mu_s, rs = rs_s;
    u16* o = ob + (size_t)row*Hz;
    o[tid]     = f2b((v0-mu)*rs*w[tid]    +b[tid]);
    o[tid+256] = f2b((v1-mu)*rs*w[tid+256]+b[tid+256]);
}

// ============ 2-phase 256xBN MFMA GEMM (T3-minimum recipe) =============
// C[N,M] = A[N,K] @ Bw[M,K]^T. BM=256, BK=64, 512 threads (8 waves).
// BN=256: wave w -> all 256 rows x cols w*32  (acc[16][2], 64 MFMA/tile)
// BN=128: wave w -> rows (w>>2)*128 x cols (w&3)*32 (acc[8][2], 32 MFMA/tile)
// Per tile: stage(next) -> ds_read+MFMA(cur) -> __syncthreads (vmcnt0+barrier).
// LDS tiles [rows][64] bf16, T2 XOR swizzle via pre-swizzled global source
// (linear global_load_lds dest) + swizzled ds_read col (involution, R4-verified).
#define EB16 0
#define EY   1
#define ERES 2

// stage 64 rows x 64 cols bf16 (8KB); 1 gload_lds per thread
__device__ __forceinline__ void stage64(const u16* __restrict__ src, int ld,
                                        int grow0, int kt, u16* ldsQ){
    int lane = threadIdx.x & 63;
    int w    = threadIdx.x >> 6;
    int r    = w*8 + (lane >> 3);                      // 0..63
    int colE = 8*((lane & 7) ^ ((lane >> 3) & 7));     // swizzled source col (elems)
    const u16* g = src + (size_t)(grow0 + r)*ld + kt + colE;
    gload_lds16(g, ldsQ + w*512);                      // +lane*16B by HW
}

template<int K, int BN, int EPI>
__global__ __launch_bounds__(512, 2)
void gemm2p(const u16* __restrict__ A, const u16* __restrict__ Bw, int M,
            u16* __restrict__ outB,
            const u16* __restrict__ fxB,        // EY: bf16 residual fx
            const float* __restrict__ Dv,       // EY
            const u16* __restrict__ resB,       // ERES
            float* __restrict__ outF)           // ERES
{
    constexpr int NT = K/64;
    constexpr int WR = (BN==256)?16:8;
    __shared__ u16 AL[2][256*64];
    __shared__ u16 BL[2][BN*64];

    // XCD-aware bijective swizzle (nwg % 8 == 0 for all our grids)
    int nx = gridDim.x, ny = gridDim.y;
    int nwg = nx*ny;
    int lid = blockIdx.x + blockIdx.y*nx;
    int cpx = nwg >> 3;
    int gdx = (lid & 7)*cpx + (lid >> 3);
    int n0 = (gdx / ny) * 256;
    int m0 = (gdx % ny) * BN;

    int l = threadIdx.x & 63;
    int w = threadIdx.x >> 6;
    int lrow  = l & 15;
    int lcol0 = ((l >> 4)*8) ^ ((l & 7) << 3);   // swizzled u16 col, k-slot 0
    int lcol1 = lcol0 ^ 32;                      // k-slot 1
    int row0w = (BN==256)? 0 : (w>>2)*128;
    int colw  = (BN==256)? w*32 : (w&3)*32;

    f32x4 acc[WR][2];
    #pragma unroll
    for (int i=0;i<WR;++i){ acc[i][0]=(f32x4)(0.f); acc[i][1]=(f32x4)(0.f); }

    // prologue: stage tile 0
    #pragma unroll
    for (int q=0;q<4;++q) stage64(A, K, n0+q*64, 0, &AL[0][q*4096]);
    #pragma unroll
    for (int q=0;q<BN/64;++q) stage64(Bw, K, m0+q*64, 0, &BL[0][q*4096]);
    __syncthreads();

    for (int T=0; T<NT; ++T){
        int buf = T & 1, nb = buf ^ 1;
        if (T+1 < NT){
            int ktn = (T+1)*64;
            #pragma unroll
            for (int q=0;q<4;++q) stage64(A, K, n0+q*64, ktn, &AL[nb][q*4096]);
            #pragma unroll
            for (int q=0;q<BN/64;++q) stage64(Bw, K, m0+q*64, ktn, &BL[nb][q*4096]);
        }
        const u16* Ab = &AL[buf][0];
        const u16* Bb = &BL[buf][0];
        bf16x8 bfr[2][2];
        #pragma unroll
        for (int fn=0; fn<2; ++fn){
            bfr[0][fn] = *(const bf16x8*)&Bb[(colw + fn*16 + lrow)*64 + lcol0];
            bfr[1][fn] = *(const bf16x8*)&Bb[(colw + fn*16 + lrow)*64 + lcol1];
        }
        #pragma unroll
        for (int mh=0; mh<WR/8; ++mh){
            #pragma unroll
            for (int ks=0; ks<2; ++ks){
                bf16x8 af[8];
                #pragma unroll
                for (int f=0;f<8;++f)
                    af[f] = *(const bf16x8*)&Ab[(row0w + mh*128 + f*16 + lrow)*64 + (ks? lcol1 : lcol0)];
                #pragma unroll
                for (int f=0;f<8;++f)
                    #pragma unroll
                    for (int fn=0;fn<2;++fn)
                        acc[mh*8+f][fn] = __builtin_amdgcn_mfma_f32_16x16x32_bf16(af[f], bfr[ks][fn], acc[mh*8+f][fn], 0,0,0);
            }
        }
        __syncthreads();   // vmcnt(0)+lgkmcnt(0)+barrier: next tile staged, cur free
    }

    // epilogue: C layout col=lane&15, row=(lane>>4)*4+q
    int er = (l >> 4) * 4;
    int ec = l & 15;
    #pragma unroll
    for (int fm=0; fm<WR; ++fm)
        #pragma unroll
        for (int fn=0; fn<2; ++fn)
            #pragma unroll
            for (int q=0; q<4; ++q){
                int n = n0 + row0w + fm*16 + er + q;
                int m = m0 + colw + fn*16 + ec;
                float v = acc[fm][fn][q];
                if (EPI == EB16){
                    outB[(size_t)n*M + m] = f2b(v);
                } else if (EPI == EY){
                    size_t idx = (size_t)n*Hz + m;
                    float fxv = b2f(fxB[idx]);
                    float y = 2.0f*v + Dv[m]*fxv;
                    outB[idx] = f2b(gelu_exact(y) + fxv);
                } else {
                    size_t idx = (size_t)n*Hz + m;
                    outF[idx] = v + b2f(resB[idx]);
                }
            }
}

// ---------------- scan (f folded in, bf16 I/O, f32 state) ----------------
// g layout: [N][1024], cols [0,512)=Re raw, [512,1024)=Im raw
__global__ __launch_bounds__(256) void scan_phase1(const u16* __restrict__ g,
                                                   const float* __restrict__ prm,
                                                   float* __restrict__ ERe,
                                                   float* __restrict__ EIm){
    int t = blockIdx.x;
    int pb = t & 1; t >>= 1;
    int c  = t % NC; t /= NC;
    int b  = t;
    int p  = pb*256 + threadIdx.x;
    size_t base = ((size_t)(b*Lz + c*CL))*1024 + p;
    float Ar = prm[p], Ai = prm[Pz+p];
    float fre = prm[2*Pz+p], fim = prm[3*Pz+p];
    float xr = 0.f, xi = 0.f;
    for (int ll = 0; ll < CL; ++ll) {
        float gr = b2f(g[base]), gi = b2f(g[base+512]);
        float br = fre*gr - fim*gi;
        float bi = fre*gi + fim*gr;
        float nr = Ar*xr - Ai*xi + br;
        float ni = Ar*xi + Ai*xr + bi;
        xr = nr; xi = ni;
        base += 1024;
    }
    size_t ci = ((size_t)(b*NC + c))*Pz + p;
    ERe[ci] = xr; EIm[ci] = xi;
}

__global__ __launch_bounds__(256) void scan_combine(const float* __restrict__ ERe,
                                                    const float* __restrict__ EIm,
                                                    const float* __restrict__ prm,
                                                    float* __restrict__ SinRe,
                                                    float* __restrict__ SinIm){
    int gt = blockIdx.x*256 + threadIdx.x;   // over B*P
    int b = gt / Pz, p = gt % Pz;
    float Ar = prm[4*Pz+p], Ai = prm[5*Pz+p];
    float Sr = 0.f, Si = 0.f;
    for (int c = 0; c < NC; ++c) {
        size_t idx = ((size_t)(b*NC + c))*Pz + p;
        SinRe[idx] = Sr; SinIm[idx] = Si;
        float er = ERe[idx], ei = EIm[idx];
        float nr = Ar*Sr - Ai*Si + er;
        float ni = Ar*Si + Ai*Sr + ei;
        Sr = nr; Si = ni;
    }
}

// overwrites g with xs (bf16, same [re|im] layout)
__global__ __launch_bounds__(256) void scan_phase2(u16* __restrict__ g,
                                                   const float* __restrict__ prm,
                                                   const float* __restrict__ SinRe,
                                                   const float* __restrict__ SinIm){
    int t = blockIdx.x;
    int pb = t & 1; t >>= 1;
    int c  = t % NC; t /= NC;
    int b  = t;
    int p  = pb*256 + threadIdx.x;
    size_t base = ((size_t)(b*Lz + c*CL))*1024 + p;
    size_t ci = ((size_t)(b*NC + c))*Pz + p;
    float Ar = prm[p], Ai = prm[Pz+p];
    float fre = prm[2*Pz+p], fim = prm[3*Pz+p];
    float xr = SinRe[ci], xi = SinIm[ci];
    for (int ll = 0; ll < CL; ++ll) {
        float gr = b2f(g[base]), gi = b2f(g[base+512]);
        float br = fre*gr - fim*gi;
        float bi = fre*gi + fim*gr;
        float nr = Ar*xr - Ai*xi + br;
        float ni = Ar*xi + Ai*xr + bi;
        xr = nr; xi = ni;
        g[base] = f2b(xr); g[base+512] = f2b(xi);
        base += 1024;
    }
}

// ---------------- GEGLU elementwise: ff = a * gelu(g) ----------------
__global__ __launch_bounds__(256) void geglu_kernel(const u16* __restrict__ e,
                                                    u16* __restrict__ ff){
    size_t i = (size_t)blockIdx.x*256 + threadIdx.x;  // over N*512
    int n = (int)(i >> 9), m = (int)(i & 511);
    float a = b2f(e[(size_t)n*1024 + m]);
    float gg = b2f(e[(size_t)n*1024 + 512 + m]);
    ff[i] = f2b(a * gelu_exact(gg));
}

extern "C" void kernel_launch(void* const* d_in, const int* in_sizes, int n_in,
                              void* d_out, int out_size, void* d_ws, size_t ws_size,
                              hipStream_t stream) {
    const float* x        = (const float*)d_in[0];
    const float* ln1_w    = (const float*)d_in[1];
    const float* ln1_b    = (const float*)d_in[2];
    const float* Lre      = (const float*)d_in[3];
    const float* Lim      = (const float*)d_in[4];
    const float* B_re     = (const float*)d_in[5];
    const float* B_im     = (const float*)d_in[6];
    const float* C_re     = (const float*)d_in[7];
    const float* C_im     = (const float*)d_in[8];
    const float* Dv       = (const float*)d_in[9];
    const float* log_step = (const float*)d_in[10];
    const float* ln2_w    = (const float*)d_in[11];
    const float* ln2_b    = (const float*)d_in[12];
    const float* W_enc    = (const float*)d_in[13];
    const float* W_dec    = (const float*)d_in[14];
    float* out = (float*)d_out;

    const size_t NH = (size_t)Nz*Hz;   // 8388608
    char* W = (char*)d_ws;
    u16*   fxb  = (u16*)  (W);                    // [N,512] bf16: fx, later ff
    u16*   g    = (u16*)  (W + NH*2);             // [N,1024] bf16: g -> xs -> e
    u16*   hb   = (u16*)  (W + NH*6);             // [N,512] bf16: h
    u16*   fx2b = (u16*)  (W + NH*8);             // [N,512] bf16: fx2
    float* ERe  = (float*)(W + NH*10);
    float* EIm  = ERe + CS;
    float* SinRe= EIm + CS;
    float* SinIm= SinRe + CS;
    float* prm  = SinIm + CS;                     // 6*Pz f32
    u16*   Bcat = (u16*)(prm + 6*Pz);             // [1024,512]
    u16*   Ccat = Bcat + 1024*512;                // [512,1024]
    u16*   Wenc = Ccat + 512*1024;                // [1024,512]
    u16*   Wdec = Wenc + 1024*512;                // [512,512]

    setup_kernel<<<dim3(2), dim3(256), 0, stream>>>(Lre, Lim, log_step, prm);

    cvt_all<<<dim3(6*1024), dim3(256), 0, stream>>>(B_re, B_im, C_re, C_im, W_enc, W_dec,
                                                    Bcat, Ccat, Wenc, Wdec);

    // LN1: x -> fxb (bf16)
    ln_kernel<float><<<dim3(Nz), dim3(256), 0, stream>>>(x, ln1_w, ln1_b, fxb);

    // GEMM1: g = fxb @ Bcat^T   [N,1024]
    gemm2p<512,256,EB16><<<dim3(Nz/256, 1024/256), dim3(512), 0, stream>>>(
        fxb, Bcat, 1024, g, nullptr, nullptr, nullptr, nullptr);

    // scan: g (raw) -> xs (in place), f-scaling applied on load
    scan_phase1<<<dim3(Bz*NC*2), dim3(256), 0, stream>>>(g, prm, ERe, EIm);
    scan_combine<<<dim3((Bz*Pz)/256), dim3(256), 0, stream>>>(ERe, EIm, prm, SinRe, SinIm);
    scan_phase2<<<dim3(Bz*NC*2), dim3(256), 0, stream>>>(g, prm, SinRe, SinIm);

    // GEMM2 (Y): h = gelu(2*(xs@Ccat^T) + D*fx) + fx -> hb (bf16)
    gemm2p<1024,128,EY><<<dim3(Nz/256, 512/128), dim3(512), 0, stream>>>(
        g, Ccat, 512, hb, fxb, Dv, nullptr, nullptr);

    // LN2: hb -> fx2b (bf16)
    ln_kernel<u16><<<dim3(Nz), dim3(256), 0, stream>>>(hb, ln2_w, ln2_b, fx2b);

    // GEMM3: e = fx2b @ Wenc^T  [N,1024]  (over g slot)
    gemm2p<512,256,EB16><<<dim3(Nz/256, 1024/256), dim3(512), 0, stream>>>(
        fx2b, Wenc, 1024, g, nullptr, nullptr, nullptr, nullptr);

    // GEGLU: ff = a * gelu(gg)  (over fxb slot)
    geglu_kernel<<<dim3((unsigned)(NH/256)), dim3(256), 0, stream>>>(g, fxb);

    // GEMM4: out = ff @ Wdec^T + fx2
    gemm2p<512,128,ERES><<<dim3(Nz/256, 512/128), dim3(512), 0, stream>>>(
        fxb, Wdec, 512, nullptr, nullptr, nullptr, fx2b, out);
}

// Round 6
// 189.310 us; speedup vs baseline: 1.2860x; 1.0344x over previous
//
#include <hip/hip_runtime.h>
#include <math.h>

// (B,L,H,P) = (4,4096,512,512)
#define Bz 4
#define Lz 4096
#define Hz 512
#define Pz 512
#define Nz (Bz*Lz)          // 16384 rows
#define CL 64               // scan chunk length
#define NC (Lz/CL)          // 64 chunks
#define CS (Bz*NC*Pz)       // 131072 carry slots
#define EPSf 1e-5f

typedef unsigned short u16;
typedef unsigned int   u32;
typedef __attribute__((ext_vector_type(8))) short bf16x8;
typedef __attribute__((ext_vector_type(4))) float f32x4;

__device__ __forceinline__ float gelu_exact(float x){
    return 0.5f * x * (1.0f + erff(x * 0.70710678118654752f));
}
__device__ __forceinline__ u16 f2b(float f){
    union { float f; u32 u; } v; v.f = f;
    u32 u = v.u;
    u32 r = (u + 0x7FFFu + ((u >> 16) & 1u)) >> 16;   // RTNE
    return (u16)r;
}
__device__ __forceinline__ float b2f(u16 h){
    union { u32 u; float f; } v; v.u = ((u32)h) << 16; return v.f;
}
__device__ __forceinline__ float cvt_in(float x){ return x; }
__device__ __forceinline__ float cvt_in(u16 x){ return b2f(x); }

__device__ __forceinline__ void gload_lds16(const u16* g, u16* l){
    __builtin_amdgcn_global_load_lds(
        (const __attribute__((address_space(1))) void*)g,
        (__attribute__((address_space(3))) void*)l, 16, 0, 0);
}

// ---------------- setup: per-state SSM params ----------------
__global__ void setup_kernel(const float* __restrict__ Lre, const float* __restrict__ Lim,
                             const float* __restrict__ log_step,
                             float* __restrict__ prm){
    int p = blockIdx.x*blockDim.x + threadIdx.x;
    if (p >= Pz) return;
    float lr = Lre[p], li = Lim[p];
    float dt = expf(log_step[p]);
    float ar = lr*dt, ai = li*dt;
    float e = expf(ar);
    float Abr = e*cosf(ai), Abi = e*sinf(ai);   // Lambda_bar
    prm[p]        = Abr;
    prm[Pz + p]   = Abi;
    float nr = Abr - 1.0f, ni = Abi;
    float d2 = lr*lr + li*li;
    prm[2*Pz + p] = (nr*lr + ni*li)/d2;   // fRe
    prm[3*Pz + p] = (ni*lr - nr*li)/d2;   // fIm
    float arC = ar*(float)CL, aiC = ai*(float)CL;
    float eC = expf(arC);
    prm[4*Pz + p] = eC*cosf(aiC);         // ApowRe
    prm[5*Pz + p] = eC*sinf(aiC);         // ApowIm
}

// ---------------- merged weight converts (one launch) ----------------
__global__ __launch_bounds__(256) void cvt_all(const float* __restrict__ B_re,
                                               const float* __restrict__ B_im,
                                               const float* __restrict__ C_re,
                                               const float* __restrict__ C_im,
                                               const float* __restrict__ W_enc,
                                               const float* __restrict__ W_dec,
                                               u16* __restrict__ Bcat,
                                               u16* __restrict__ Ccat,
                                               u16* __restrict__ Wenc,
                                               u16* __restrict__ Wdec){
    const int Q = 512*512;
    int i = blockIdx.x*256 + threadIdx.x;
    if (i < Q){ Bcat[i] = f2b(B_re[i]); return; }
    i -= Q;
    if (i < Q){ Bcat[Q + i] = f2b(B_im[i]); return; }
    i -= Q;
    if (i < Q){
        int h = i >> 9, p = i & 511;
        Ccat[(size_t)h*1024 + p]       = f2b(C_re[i]);
        Ccat[(size_t)h*1024 + 512 + p] = f2b(-C_im[i]);
        return;
    }
    i -= Q;
    if (i < 2*Q){ Wenc[i] = f2b(W_enc[i]); return; }
    i -= 2*Q;
    Wdec[i] = f2b(W_dec[i]);
}

// ---------------- LayerNorm: (f32|bf16) in -> bf16 out ----------------
template<typename T>
__global__ __launch_bounds__(256) void ln_kernel(const T* __restrict__ in,
                                                 const float* __restrict__ w,
                                                 const float* __restrict__ b,
                                                 u16* __restrict__ ob){
    int row = blockIdx.x;
    int tid = threadIdx.x;
    const T* r = in + (size_t)row*Hz;
    float v0 = cvt_in(r[tid]), v1 = cvt_in(r[tid+256]);
    float s = v0+v1, q = v0*v0+v1*v1;
    #pragma unroll
    for (int o=32;o;o>>=1){ s += __shfl_down(s,o); q += __shfl_down(q,o); }
    __shared__ float ss[4], sq[4];
    __shared__ float mu_s, rs_s;
    int wid = tid>>6, lane = tid&63;
    if (lane==0){ ss[wid]=s; sq[wid]=q; }
    __syncthreads();
    if (tid==0){
        float S=ss[0]+ss[1]+ss[2]+ss[3];
        float Q=sq[0]+sq[1]+sq[2]+sq[3];
        float mu = S/(float)Hz;
        float var = Q/(float)Hz - mu*mu;
        mu_s = mu; rs_s = rsqrtf(var + EPSf);
    }
    __syncthreads();
    float mu = mu_s, rs = rs_s;
    u16* o = ob + (size_t)row*Hz;
    o[tid]     = f2b((v0-mu)*rs*w[tid]    +b[tid]);
    o[tid+256] = f2b((v1-mu)*rs*w[tid+256]+b[tid+256]);
}

// ============ 2-phase 128x128 MFMA GEMM, 2 blocks/CU =============
// C[N,M] = A[N,K] @ Bw[M,K]^T. BM=BN=128, BK=64, 256 threads (4 waves).
// Wave w: all 128 rows x cols [w*32, w*32+32)  -> acc[8][2] f32x4 (64 VGPR).
// LDS: 2 x (16KB A + 16KB B) = 64KB -> 2 blocks/CU; grids 512-1024 blocks.
// Per tile: stage(next) -> ds_read+32 MFMA(cur) -> __syncthreads. Cross-block
// overlap (m114) hides the vmcnt drain; T2 swizzle keeps ds_read conflict-free.
#define EB16 0
#define EY   1
#define ERES 2

// stage 128 rows x 64 cols bf16 (16KB); 4 gload_lds per thread (256 thr)
__device__ __forceinline__ void stage128(const u16* __restrict__ src, int ld,
                                         int grow0, int kt, u16* lds){
    int lane = threadIdx.x & 63;
    int w    = threadIdx.x >> 6;                       // 0..3
    #pragma unroll
    for (int q = 0; q < 4; ++q){
        int c = w + q*4;                               // 1KB chunk id, 0..15 (8 rows)
        int r = c*8 + (lane >> 3);                     // row 0..127
        int colE = 8*((lane & 7) ^ ((lane >> 3) & 7)); // swizzled source col (elems)
        const u16* g = src + (size_t)(grow0 + r)*ld + kt + colE;
        gload_lds16(g, lds + c*512);                   // wave-uniform base + lane*16B
    }
}

template<int K, int EPI>
__global__ __launch_bounds__(256, 2)
void gemm2p(const u16* __restrict__ A, const u16* __restrict__ Bw, int M,
            u16* __restrict__ outB,
            const u16* __restrict__ fxB,        // EY: bf16 residual fx
            const float* __restrict__ Dv,       // EY
            const u16* __restrict__ resB,       // ERES
            float* __restrict__ outF)           // ERES
{
    constexpr int NT = K/64;
    __shared__ u16 AL[2][128*64];
    __shared__ u16 BL[2][128*64];

    // XCD-aware bijective swizzle (nwg % 8 == 0 for all our grids)
    int nx = gridDim.x, ny = gridDim.y;
    int nwg = nx*ny;
    int lid = blockIdx.x + blockIdx.y*nx;
    int cpx = nwg >> 3;
    int gdx = (lid & 7)*cpx + (lid >> 3);
    int n0 = (gdx / ny) * 128;
    int m0 = (gdx % ny) * 128;

    int l = threadIdx.x & 63;
    int w = threadIdx.x >> 6;
    int lrow  = l & 15;
    int lcol0 = ((l >> 4)*8) ^ ((l & 7) << 3);   // swizzled u16 col, k-slot 0
    int lcol1 = lcol0 ^ 32;                      // k-slot 1
    int colw  = w*32;

    f32x4 acc[8][2];
    #pragma unroll
    for (int i=0;i<8;++i){ acc[i][0]=(f32x4)(0.f); acc[i][1]=(f32x4)(0.f); }

    // prologue: stage tile 0
    stage128(A,  K, n0, 0, &AL[0][0]);
    stage128(Bw, K, m0, 0, &BL[0][0]);
    __syncthreads();

    for (int T=0; T<NT; ++T){
        int buf = T & 1, nb = buf ^ 1;
        if (T+1 < NT){
            int ktn = (T+1)*64;
            stage128(A,  K, n0, ktn, &AL[nb][0]);
            stage128(Bw, K, m0, ktn, &BL[nb][0]);
        }
        const u16* Ab = &AL[buf][0];
        const u16* Bb = &BL[buf][0];
        bf16x8 bfr[2][2];
        #pragma unroll
        for (int fn=0; fn<2; ++fn){
            bfr[0][fn] = *(const bf16x8*)&Bb[(colw + fn*16 + lrow)*64 + lcol0];
            bfr[1][fn] = *(const bf16x8*)&Bb[(colw + fn*16 + lrow)*64 + lcol1];
        }
        #pragma unroll
        for (int f=0; f<8; ++f){
            bf16x8 a0 = *(const bf16x8*)&Ab[(f*16 + lrow)*64 + lcol0];
            bf16x8 a1 = *(const bf16x8*)&Ab[(f*16 + lrow)*64 + lcol1];
            #pragma unroll
            for (int fn=0; fn<2; ++fn){
                acc[f][fn] = __builtin_amdgcn_mfma_f32_16x16x32_bf16(a0, bfr[0][fn], acc[f][fn], 0,0,0);
                acc[f][fn] = __builtin_amdgcn_mfma_f32_16x16x32_bf16(a1, bfr[1][fn], acc[f][fn], 0,0,0);
            }
        }
        __syncthreads();   // vmcnt(0)+lgkmcnt(0)+barrier; other resident block overlaps
    }

    // epilogue: C layout col=lane&15, row=(lane>>4)*4+q
    int er = (l >> 4) * 4;
    int ec = l & 15;
    #pragma unroll
    for (int fm=0; fm<8; ++fm)
        #pragma unroll
        for (int fn=0; fn<2; ++fn)
            #pragma unroll
            for (int q=0; q<4; ++q){
                int n = n0 + fm*16 + er + q;
                int m = m0 + colw + fn*16 + ec;
                float v = acc[fm][fn][q];
                if (EPI == EB16){
                    outB[(size_t)n*M + m] = f2b(v);
                } else if (EPI == EY){
                    size_t idx = (size_t)n*Hz + m;
                    float fxv = b2f(fxB[idx]);
                    float y = 2.0f*v + Dv[m]*fxv;
                    outB[idx] = f2b(gelu_exact(y) + fxv);
                } else {
                    size_t idx = (size_t)n*Hz + m;
                    outF[idx] = v + b2f(resB[idx]);
                }
            }
}

// ---------------- scan (f folded in, bf16 I/O, f32 state) ----------------
// g layout: [N][1024], cols [0,512)=Re raw, [512,1024)=Im raw
__global__ __launch_bounds__(256) void scan_phase1(const u16* __restrict__ g,
                                                   const float* __restrict__ prm,
                                                   float* __restrict__ ERe,
                                                   float* __restrict__ EIm){
    int t = blockIdx.x;
    int pb = t & 1; t >>= 1;
    int c  = t % NC; t /= NC;
    int b  = t;
    int p  = pb*256 + threadIdx.x;
    size_t base = ((size_t)(b*Lz + c*CL))*1024 + p;
    float Ar = prm[p], Ai = prm[Pz+p];
    float fre = prm[2*Pz+p], fim = prm[3*Pz+p];
    float xr = 0.f, xi = 0.f;
    for (int ll = 0; ll < CL; ++ll) {
        float gr = b2f(g[base]), gi = b2f(g[base+512]);
        float br = fre*gr - fim*gi;
        float bi = fre*gi + fim*gr;
        float nr = Ar*xr - Ai*xi + br;
        float ni = Ar*xi + Ai*xr + bi;
        xr = nr; xi = ni;
        base += 1024;
    }
    size_t ci = ((size_t)(b*NC + c))*Pz + p;
    ERe[ci] = xr; EIm[ci] = xi;
}

__global__ __launch_bounds__(256) void scan_combine(const float* __restrict__ ERe,
                                                    const float* __restrict__ EIm,
                                                    const float* __restrict__ prm,
                                                    float* __restrict__ SinRe,
                                                    float* __restrict__ SinIm){
    int gt = blockIdx.x*256 + threadIdx.x;   // over B*P
    int b = gt / Pz, p = gt % Pz;
    float Ar = prm[4*Pz+p], Ai = prm[5*Pz+p];
    float Sr = 0.f, Si = 0.f;
    for (int c = 0; c < NC; ++c) {
        size_t idx = ((size_t)(b*NC + c))*Pz + p;
        SinRe[idx] = Sr; SinIm[idx] = Si;
        float er = ERe[idx], ei = EIm[idx];
        float nr = Ar*Sr - Ai*Si + er;
        float ni = Ar*Si + Ai*Sr + ei;
        Sr = nr; Si = ni;
    }
}

// overwrites g with xs (bf16, same [re|im] layout)
__global__ __launch_bounds__(256) void scan_phase2(u16* __restrict__ g,
                                                   const float* __restrict__ prm,
                                                   const float* __restrict__ SinRe,
                                                   const float* __restrict__ SinIm){
    int t = blockIdx.x;
    int pb = t & 1; t >>= 1;
    int c  = t % NC; t /= NC;
    int b  = t;
    int p  = pb*256 + threadIdx.x;
    size_t base = ((size_t)(b*Lz + c*CL))*1024 + p;
    size_t ci = ((size_t)(b*NC + c))*Pz + p;
    float Ar = prm[p], Ai = prm[Pz+p];
    float fre = prm[2*Pz+p], fim = prm[3*Pz+p];
    float xr = SinRe[ci], xi = SinIm[ci];
    for (int ll = 0; ll < CL; ++ll) {
        float gr = b2f(g[base]), gi = b2f(g[base+512]);
        float br = fre*gr - fim*gi;
        float bi = fre*gi + fim*gr;
        float nr = Ar*xr - Ai*xi + br;
        float ni = Ar*xi + Ai*xr + bi;
        xr = nr; xi = ni;
        g[base] = f2b(xr); g[base+512] = f2b(xi);
        base += 1024;
    }
}

// ---------------- GEGLU elementwise: ff = a * gelu(g) ----------------
__global__ __launch_bounds__(256) void geglu_kernel(const u16* __restrict__ e,
                                                    u16* __restrict__ ff){
    size_t i = (size_t)blockIdx.x*256 + threadIdx.x;  // over N*512
    int n = (int)(i >> 9), m = (int)(i & 511);
    float a = b2f(e[(size_t)n*1024 + m]);
    float gg = b2f(e[(size_t)n*1024 + 512 + m]);
    ff[i] = f2b(a * gelu_exact(gg));
}

extern "C" void kernel_launch(void* const* d_in, const int* in_sizes, int n_in,
                              void* d_out, int out_size, void* d_ws, size_t ws_size,
                              hipStream_t stream) {
    const float* x        = (const float*)d_in[0];
    const float* ln1_w    = (const float*)d_in[1];
    const float* ln1_b    = (const float*)d_in[2];
    const float* Lre      = (const float*)d_in[3];
    const float* Lim      = (const float*)d_in[4];
    const float* B_re     = (const float*)d_in[5];
    const float* B_im     = (const float*)d_in[6];
    const float* C_re     = (const float*)d_in[7];
    const float* C_im     = (const float*)d_in[8];
    const float* Dv       = (const float*)d_in[9];
    const float* log_step = (const float*)d_in[10];
    const float* ln2_w    = (const float*)d_in[11];
    const float* ln2_b    = (const float*)d_in[12];
    const float* W_enc    = (const float*)d_in[13];
    const float* W_dec    = (const float*)d_in[14];
    float* out = (float*)d_out;

    const size_t NH = (size_t)Nz*Hz;   // 8388608
    char* W = (char*)d_ws;
    u16*   fxb  = (u16*)  (W);                    // [N,512] bf16: fx, later ff
    u16*   g    = (u16*)  (W + NH*2);             // [N,1024] bf16: g -> xs -> e
    u16*   hb   = (u16*)  (W + NH*6);             // [N,512] bf16: h
    u16*   fx2b = (u16*)  (W + NH*8);             // [N,512] bf16: fx2
    float* ERe  = (float*)(W + NH*10);
    float* EIm  = ERe + CS;
    float* SinRe= EIm + CS;
    float* SinIm= SinRe + CS;
    float* prm  = SinIm + CS;                     // 6*Pz f32
    u16*   Bcat = (u16*)(prm + 6*Pz);             // [1024,512]
    u16*   Ccat = Bcat + 1024*512;                // [512,1024]
    u16*   Wenc = Ccat + 512*1024;                // [1024,512]
    u16*   Wdec = Wenc + 1024*512;                // [512,512]

    setup_kernel<<<dim3(2), dim3(256), 0, stream>>>(Lre, Lim, log_step, prm);

    cvt_all<<<dim3(6*1024), dim3(256), 0, stream>>>(B_re, B_im, C_re, C_im, W_enc, W_dec,
                                                    Bcat, Ccat, Wenc, Wdec);

    // LN1: x -> fxb (bf16)
    ln_kernel<float><<<dim3(Nz), dim3(256), 0, stream>>>(x, ln1_w, ln1_b, fxb);

    // GEMM1: g = fxb @ Bcat^T   [N,1024]   grid 128x8 = 1024 blocks
    gemm2p<512,EB16><<<dim3(Nz/128, 1024/128), dim3(256), 0, stream>>>(
        fxb, Bcat, 1024, g, nullptr, nullptr, nullptr, nullptr);

    // scan: g (raw) -> xs (in place), f-scaling applied on load
    scan_phase1<<<dim3(Bz*NC*2), dim3(256), 0, stream>>>(g, prm, ERe, EIm);
    scan_combine<<<dim3((Bz*Pz)/256), dim3(256), 0, stream>>>(ERe, EIm, prm, SinRe, SinIm);
    scan_phase2<<<dim3(Bz*NC*2), dim3(256), 0, stream>>>(g, prm, SinRe, SinIm);

    // GEMM2 (Y): h = gelu(2*(xs@Ccat^T) + D*fx) + fx -> hb   grid 128x4 = 512
    gemm2p<1024,EY><<<dim3(Nz/128, 512/128), dim3(256), 0, stream>>>(
        g, Ccat, 512, hb, fxb, Dv, nullptr, nullptr);

    // LN2: hb -> fx2b (bf16)
    ln_kernel<u16><<<dim3(Nz), dim3(256), 0, stream>>>(hb, ln2_w, ln2_b, fx2b);

    // GEMM3: e = fx2b @ Wenc^T  [N,1024]  grid 128x8 = 1024
    gemm2p<512,EB16><<<dim3(Nz/128, 1024/128), dim3(256), 0, stream>>>(
        fx2b, Wenc, 1024, g, nullptr, nullptr, nullptr, nullptr);

    // GEGLU: ff = a * gelu(gg)  (over fxb slot)
    geglu_kernel<<<dim3((unsigned)(NH/256)), dim3(256), 0, stream>>>(g, fxb);

    // GEMM4: out = ff @ Wdec^T + fx2   grid 128x4 = 512
    gemm2p<512,ERES><<<dim3(Nz/128, 512/128), dim3(256), 0, stream>>>(
        fxb, Wdec, 512, nullptr, nullptr, nullptr, fx2b, out);
}